// Round 3
// baseline (365.126 us; speedup 1.0000x reference)
//
#include <hip/hip_runtime.h>

constexpr int Bn  = 8;
constexpr int Ln  = 2048;
constexpr int En  = 4096;
constexpr int TDn = 768;   // TOKEN_DIM
constexpr int EDn = 256;   // EDGE_DIM
constexpr int Hn  = 128;   // HIDDEN

// ws layout (float offsets)
constexpr int OFF_CNT = 0;       // 8 uint32 arrival counters (per batch)
constexpr int OFF_DEN = 8;       // 8 softmax denominators
constexpr int OFF_V1  = 16;      // 768: W[:768,:128] . a1
constexpr int OFF_T   = 1024;    // 8*768 exp-weighted token sums (atomic)
constexpr int OFF_ES  = 8192;    // 8*256 edge column sums (atomic)
constexpr int OFF_ROW = 10752;   // 8*128 final rows

// ===========================================================================
// K_0: blocks 0..191 compute v1[d] = W[d,:128].a1 (one wave per d);
//      blocks 192..231 zero the atomic accumulator regions
//      ([0,16) counters+den, [1024,10240) t/es).
// ===========================================================================
__global__ __launch_bounds__(256)
void K_0(const float* __restrict__ W, const float* __restrict__ a,
         float* __restrict__ ws)
{
    const int tid = threadIdx.x, wv = tid >> 6, lane = tid & 63;
    if (blockIdx.x < 192) {
        int d = blockIdx.x * 4 + wv;               // 0..767
        float acc = W[d * Hn + lane]      * a[lane]
                  + W[d * Hn + 64 + lane] * a[64 + lane];
        #pragma unroll
        for (int off = 32; off > 0; off >>= 1)
            acc += __shfl_down(acc, off, 64);
        if (lane == 0) ws[OFF_V1 + d] = acc;
    } else {
        int i = (blockIdx.x - 192) * 256 + tid;    // 0..10239
        if (i < 9232) {
            int z = (i < 16) ? i : (1008 + i);     // [0,16) U [1024,10240)
            ws[z] = 0.0f;
        }
    }
}

// ===========================================================================
// K_1: 2048 blocks, parity-interleaved:
//   even bi -> token chunk (16 rows): scores + exp-weighted sums -> atomics
//   odd  bi -> edge chunk (32 rows): column sums -> atomics
// Each block then bumps its batch counter (post-threadfence); the 256th
// block per batch finalizes: normalizes, does the 1024x128 matvec against
// W (L2-hot), writes row[b][128] to ws.
// ===========================================================================
__global__ __launch_bounds__(256)
void K_1(const float* __restrict__ token, const float* __restrict__ edge,
         const float* __restrict__ W, float* __restrict__ ws)
{
    const int tid = threadIdx.x, wv = tid >> 6, lane = tid & 63;
    const int hid = blockIdx.x >> 1;               // 0..1023
    const int b = hid >> 7, chunk = hid & 127;
    __shared__ __align__(16) float sm[1280];       // 5 KB arena
    __shared__ int s_last;

    if ((blockIdx.x & 1) == 0) {
        // ---- token chunk: 16 rows ---------------------------------------
        const size_t row0 = (size_t)(b * Ln + chunk * 16);

        if (tid < TDn / 4) ((float4*)sm)[tid] = ((const float4*)(ws + OFF_V1))[tid];
        __syncthreads();
        const float4* V1 = (const float4*)sm;

        // scores. No max-subtraction: |s| = |token . v1| <~ 1 (v1 ~4e-3),
        // expf cannot overflow and softmax(s) == softmax(s - m) exactly.
        #pragma unroll
        for (int i = 0; i < 4; ++i) {              // 4 rows per wave
            int li = wv * 4 + i;
            const float4* t4 = (const float4*)token + (row0 + li) * (TDn / 4);
            float acc = 0.f;
            #pragma unroll
            for (int j = 0; j < 3; ++j) {
                float4 t = t4[lane + 64 * j];
                float4 v = V1[lane + 64 * j];
                acc += t.x * v.x + t.y * v.y + t.z * v.z + t.w * v.w;
            }
            #pragma unroll
            for (int off = 32; off > 0; off >>= 1)
                acc += __shfl_down(acc, off, 64);
            if (lane == 0) sm[768 + li] = acc;
        }
        __syncthreads();
        if (tid < 16) sm[784 + tid] = expf(sm[768 + tid]);
        __syncthreads();

        float sum = 0.f;
        #pragma unroll
        for (int l = 0; l < 16; ++l) sum += sm[784 + l];

        // exp-weighted token sum (tile is L1/L2-warm from the score pass)
        const float* tok = token + row0 * TDn;
        float a0 = 0.f, a1 = 0.f, a2 = 0.f;
        #pragma unroll 4
        for (int l = 0; l < 16; ++l) {
            float e = sm[784 + l];
            const float* r = tok + (size_t)l * TDn;
            a0 += e * r[tid];
            a1 += e * r[tid + 256];
            a2 += e * r[tid + 512];
        }
        float* tacc = ws + OFF_T + b * TDn;
        atomicAdd(tacc + tid,       a0);
        atomicAdd(tacc + tid + 256, a1);
        atomicAdd(tacc + tid + 512, a2);
        if (tid == 0) atomicAdd(ws + OFF_DEN + b, sum);
    } else {
        // ---- edge chunk: 32 rows, 8 per wave ----------------------------
        const float4* e4 = (const float4*)edge
                         + ((size_t)(b * En + chunk * 32 + wv * 8)) * (EDn / 4) + lane;
        float4 acc = {0.f, 0.f, 0.f, 0.f};
        #pragma unroll
        for (int i = 0; i < 8; ++i) {
            float4 v = e4[(size_t)i * (EDn / 4)];
            acc.x += v.x; acc.y += v.y; acc.z += v.z; acc.w += v.w;
        }
        float* sr = sm + wv * 256 + lane * 4;      // column lane*4+k of wave wv
        sr[0] = acc.x; sr[1] = acc.y; sr[2] = acc.z; sr[3] = acc.w;
        __syncthreads();
        float v = sm[tid] + sm[256 + tid] + sm[512 + tid] + sm[768 + tid];
        atomicAdd(ws + OFF_ES + b * EDn + tid, v);
    }

    // ---- arrival + last-block finalize ----------------------------------
    __syncthreads();
    __threadfence();                               // release our atomics
    if (tid == 0) {
        unsigned old = atomicAdd((unsigned*)ws + OFF_CNT + b, 1u);
        s_last = (old == 255u);                    // 128 token + 128 edge
    }
    __syncthreads();
    if (!s_last) return;
    __threadfence();                               // acquire others' atomics

    float invden = 1.0f / ws[OFF_DEN + b];
    const float* tacc = ws + OFF_T + b * TDn;
    sm[tid]       = tacc[tid]       * invden;
    sm[tid + 256] = tacc[tid + 256] * invden;
    sm[tid + 512] = tacc[tid + 512] * invden;
    sm[768 + tid] = ws[OFF_ES + b * EDn + tid] * (1.0f / En);
    __syncthreads();

    // row[h] = sm[0:1024] . W[:,h]; 2 threads per h
    const int h = tid & 127, half = tid >> 7;
    const float* w = W + (size_t)(half * 512) * Hn + h;
    float acc = 0.f;
    #pragma unroll 8
    for (int i = 0; i < 512; ++i)
        acc += sm[half * 512 + i] * w[(size_t)i * Hn];
    sm[1024 + tid] = acc;
    __syncthreads();
    if (tid < 128)
        ws[OFF_ROW + b * Hn + tid] = sm[1024 + tid] + sm[1024 + 128 + tid];
}

// ===========================================================================
// K_2: pure broadcast of row[b][128] to out[b,i,:]. 2048 x 256, one float4
// per thread = 8.4 MB of coalesced stores; row reads are L2/L3-hot.
// ===========================================================================
__global__ __launch_bounds__(256)
void K_2(const float* __restrict__ ws, float4* __restrict__ out)
{
    int idx = blockIdx.x * 256 + threadIdx.x;      // 0..524287
    int b = idx >> 16;                             // / (L*H/4)
    out[idx] = ((const float4*)(ws + OFF_ROW))[b * (Hn / 4) + (idx & (Hn / 4 - 1))];
}

extern "C" void kernel_launch(void* const* d_in, const int* in_sizes, int n_in,
                              void* d_out, int out_size, void* d_ws, size_t ws_size,
                              hipStream_t stream) {
    const float* token = (const float*)d_in[0];
    const float* edge  = (const float*)d_in[1];
    const float* W     = (const float*)d_in[2];
    const float* a     = (const float*)d_in[3];
    // d_in[4] (b_attn) cancels in the softmax — unused.
    float* ws   = (float*)d_ws;
    float4* out = (float4*)d_out;

    K_0<<<232,  256, 0, stream>>>(W, a, ws);
    K_1<<<2048, 256, 0, stream>>>(token, edge, W, ws);
    K_2<<<2048, 256, 0, stream>>>(ws, out);
}

// Round 4
// 128.920 us; speedup vs baseline: 2.8322x; 2.8322x over previous
//
#include <hip/hip_runtime.h>

constexpr int Bn  = 8;
constexpr int Ln  = 2048;
constexpr int En  = 4096;
constexpr int TDn = 768;   // TOKEN_DIM
constexpr int EDn = 256;   // EDGE_DIM
constexpr int Hn  = 128;   // HIDDEN

// ws layout (float offsets) — no atomics, everything rec-written then combined
constexpr int OFF_V1   = 0;                      // 768: W[:768,:].a1
constexpr int OFF_TREC = 1024;                   // 512 recs * 772 {den,_,_,_,vec768}
constexpr int TRECF    = 772;                    // float stride (16B-aligned)
constexpr int OFF_EREC = OFF_TREC + 512 * TRECF; // 512 recs * 256
// total ~2.1 MB of ws

// ===========================================================================
// K_0: v1[d] = W[d,:128] . a1 — one wave per d, 192 blocks (proven R0 code)
// ===========================================================================
__global__ __launch_bounds__(256)
void K_0(const float* __restrict__ W, const float* __restrict__ a,
         float* __restrict__ ws)
{
    const int tid = threadIdx.x, wv = tid >> 6, lane = tid & 63;
    int d = blockIdx.x * 4 + wv;                   // 0..767
    float acc = W[d * Hn + lane]      * a[lane]
              + W[d * Hn + 64 + lane] * a[64 + lane];
    #pragma unroll
    for (int off = 32; off > 0; off >>= 1)
        acc += __shfl_down(acc, off, 64);
    if (lane == 0) ws[OFF_V1 + d] = acc;
}

// ===========================================================================
// K_1: 1024 blocks.
//   bi <  512: token chunk, 32 rows (8 per wave), fully register-resident:
//              load row (3 float4/lane) -> butterfly dot -> expf -> FMA acc.
//              One HBM pass. Cross-wave LDS reduce -> rec {den, vec768}.
//   bi >= 512: edge chunk, 64 rows (16 per wave), float4 column sums -> rec.
// ===========================================================================
__global__ __launch_bounds__(256)
void K_1(const float* __restrict__ token, const float* __restrict__ edge,
         float* __restrict__ ws)
{
    const int tid = threadIdx.x, wv = tid >> 6, lane = tid & 63;
    const int bi = blockIdx.x;
    __shared__ __align__(16) float4 smf[4 * 192];  // 12 KB (token path)
    __shared__ float sm_den[4];

    if (bi < 512) {
        const int b = bi >> 6, chunk = bi & 63;
        const size_t row0 = (size_t)b * Ln + chunk * 32 + wv * 8;

        // v1 fragment for this lane's columns (L2/L3-hot, 48 B)
        const float4* v1_4 = (const float4*)(ws + OFF_V1);
        float4 u0 = v1_4[lane], u1 = v1_4[64 + lane], u2 = v1_4[128 + lane];

        float4 a0 = {0,0,0,0}, a1 = {0,0,0,0}, a2 = {0,0,0,0};
        float esum = 0.f;
        const float4* t4 = (const float4*)token + row0 * (TDn / 4);
        #pragma unroll
        for (int i = 0; i < 8; ++i) {
            float4 v0 = t4[i * 192 + lane];
            float4 v1 = t4[i * 192 + 64 + lane];
            float4 v2 = t4[i * 192 + 128 + lane];
            float d = v0.x*u0.x + v0.y*u0.y + v0.z*u0.z + v0.w*u0.w
                    + v1.x*u1.x + v1.y*u1.y + v1.z*u1.z + v1.w*u1.w
                    + v2.x*u2.x + v2.y*u2.y + v2.z*u2.z + v2.w*u2.w;
            #pragma unroll
            for (int off = 32; off > 0; off >>= 1)
                d += __shfl_xor(d, off, 64);
            // No max-subtraction: |d| = |token . v1| <~ 1 (v1 ~4e-3);
            // expf cannot overflow and softmax is exact without it.
            float e = expf(d);
            esum += e;
            a0.x += e*v0.x; a0.y += e*v0.y; a0.z += e*v0.z; a0.w += e*v0.w;
            a1.x += e*v1.x; a1.y += e*v1.y; a1.z += e*v1.z; a1.w += e*v1.w;
            a2.x += e*v2.x; a2.y += e*v2.y; a2.z += e*v2.z; a2.w += e*v2.w;
        }
        smf[wv * 192 + lane]       = a0;
        smf[wv * 192 + 64 + lane]  = a1;
        smf[wv * 192 + 128 + lane] = a2;
        if (lane == 0) sm_den[wv] = esum;
        __syncthreads();

        float* rec = ws + OFF_TREC + (size_t)bi * TRECF;
        if (tid < 192) {
            float4 r  = smf[tid];
            float4 r1 = smf[192 + tid], r2 = smf[384 + tid], r3 = smf[576 + tid];
            r.x += r1.x + r2.x + r3.x;  r.y += r1.y + r2.y + r3.y;
            r.z += r1.z + r2.z + r3.z;  r.w += r1.w + r2.w + r3.w;
            ((float4*)(rec + 4))[tid] = r;
        }
        if (tid == 0)
            rec[0] = sm_den[0] + sm_den[1] + sm_den[2] + sm_den[3];
    } else {
        const int eb = bi - 512;                   // 0..511
        const int b = eb >> 6, chunk = eb & 63;
        const size_t row0 = (size_t)b * En + chunk * 64 + wv * 16;
        const float4* e4 = (const float4*)edge + row0 * (EDn / 4) + lane;
        float4 acc = {0,0,0,0};
        #pragma unroll
        for (int i = 0; i < 16; ++i) {
            float4 v = e4[(size_t)i * (EDn / 4)];
            acc.x += v.x; acc.y += v.y; acc.z += v.z; acc.w += v.w;
        }
        smf[wv * 64 + lane] = acc;
        __syncthreads();
        if (tid < 64) {
            float4 r0 = smf[tid],       r1 = smf[64 + tid],
                   r2 = smf[128 + tid], r3 = smf[192 + tid];
            float4 s = {r0.x + r1.x + r2.x + r3.x, r0.y + r1.y + r2.y + r3.y,
                        r0.z + r1.z + r2.z + r3.z, r0.w + r1.w + r2.w + r3.w};
            ((float4*)(ws + OFF_EREC))[(size_t)eb * 64 + tid] = s;
        }
    }
}

// ===========================================================================
// K_2: 256 blocks = 8 batches x 32 output slices. Each block:
//   - combines its batch's 64 token recs (threads 0..191, 64 float4 each)
//     + 64 edge recs (threads 192..255) + den (threads 0..63, 1 load each),
//   - does the 1024x128 matvec with float4 W loads (L2-hot),
//   - writes its 64-row slice of the broadcast output (0.26 MB, coalesced).
// Per-thread load counts are small (~64-128 float4) => not latency-bound.
// ===========================================================================
__global__ __launch_bounds__(256)
void K_2(const float* __restrict__ W, const float* __restrict__ ws,
         float4* __restrict__ out)
{
    __shared__ __align__(16) float s_c[1024];
    __shared__ __align__(16) float4 smp[256];
    __shared__ __align__(16) float4 s_row[32];
    __shared__ float s_den;
    const int tid = threadIdx.x;
    const int b = blockIdx.x >> 5, slice = blockIdx.x & 31;

    float dpart = (tid < 64)
        ? ws[OFF_TREC + (size_t)(b * 64 + tid) * TRECF] : 0.f;

    float4 acc = {0,0,0,0};
    if (tid < 192) {
        const float4* rb = (const float4*)(ws + OFF_TREC)
                         + (size_t)(b * 64) * (TRECF / 4) + 1 + tid;
        #pragma unroll 8
        for (int k = 0; k < 64; ++k) {
            float4 v = rb[(size_t)k * (TRECF / 4)];
            acc.x += v.x; acc.y += v.y; acc.z += v.z; acc.w += v.w;
        }
    } else {
        const float4* rb = (const float4*)(ws + OFF_EREC)
                         + (size_t)(b * 64) * (EDn / 4) + (tid - 192);
        #pragma unroll 8
        for (int k = 0; k < 64; ++k) {
            float4 v = rb[(size_t)k * (EDn / 4)];
            acc.x += v.x; acc.y += v.y; acc.z += v.z; acc.w += v.w;
        }
    }
    if (tid < 64) {
        #pragma unroll
        for (int off = 32; off > 0; off >>= 1)
            dpart += __shfl_xor(dpart, off, 64);
        if (tid == 0) s_den = dpart;
    }
    __syncthreads();

    float scale = (tid < 192) ? (1.0f / s_den) : (1.0f / En);
    float4 c = {acc.x * scale, acc.y * scale, acc.z * scale, acc.w * scale};
    ((float4*)s_c)[tid] = c;
    __syncthreads();

    // matvec: row[4hq..4hq+3] partial over d-range dg*128..+128
    const int hq = tid & 31, dg = tid >> 5;
    const float4* W4 = (const float4*)W;
    const float* cp = s_c + dg * 128;
    float4 m = {0,0,0,0};
    #pragma unroll 8
    for (int i = 0; i < 128; ++i) {
        float cv = cp[i];
        float4 w = W4[(size_t)(dg * 128 + i) * (Hn / 4) + hq];
        m.x += cv * w.x; m.y += cv * w.y; m.z += cv * w.z; m.w += cv * w.w;
    }
    smp[tid] = m;
    __syncthreads();
    if (tid < 32) {
        float4 r = smp[tid];
        #pragma unroll
        for (int g = 1; g < 8; ++g) {
            float4 v = smp[g * 32 + tid];
            r.x += v.x; r.y += v.y; r.z += v.z; r.w += v.w;
        }
        s_row[tid] = r;
    }
    __syncthreads();

    // output slice: 64 rows x 128 floats, coalesced float4 stores
    float4* ob = out + ((size_t)b * Ln + slice * 64) * (Hn / 4);
    #pragma unroll
    for (int k = 0; k < 8; ++k) {
        int f = k * 256 + tid;                     // row*32 + col4
        ob[f] = s_row[f & 31];
    }
}

extern "C" void kernel_launch(void* const* d_in, const int* in_sizes, int n_in,
                              void* d_out, int out_size, void* d_ws, size_t ws_size,
                              hipStream_t stream) {
    const float* token = (const float*)d_in[0];
    const float* edge  = (const float*)d_in[1];
    const float* W     = (const float*)d_in[2];
    const float* a     = (const float*)d_in[3];
    // d_in[4] (b_attn) cancels in the softmax — unused.
    float* ws   = (float*)d_ws;
    float4* out = (float4*)d_out;

    K_0<<<192,  256, 0, stream>>>(W, a, ws);
    K_1<<<1024, 256, 0, stream>>>(token, edge, ws);
    K_2<<<256,  256, 0, stream>>>(W, ws, out);
}